// Round 16
// baseline (257.591 us; speedup 1.0000x reference)
//
#include <hip/hip_runtime.h>
#include <hip/hip_fp16.h>

#define B_ 16
#define N_ 785
#define NP 800          // padded per-batch rows (multiple of 4; 16*800=12800)
#define C_ 768
#define H_ 12
#define HD_ 64
#define P_ 48
#define M_ (B_*N_)      // 12560
#define MP_ (B_*NP)     // 12800 = 100 * 128
#define POSW 832        // padded row stride (halves) for pos bias (13*64)
#define VTW  832        // padded row stride (halves) for V^T
#define SLOG2E 0.1803368801111244f   // (hd^-0.5) * log2(e)

// ws layout (fp16 element offsets)
#define OFF_Q   0                    //  9,646,080
#define OFF_K   9646080              //  9,646,080
#define OFF_VT  19292160             // 10,223,616 (16*12*64*832)
#define OFF_POS 29515776             //  7,837,440 (12*785*832)
#define OFF_AO  37353216             //  9,646,080 (attn out, f16)
#define OFF_WQ  47085312             //  1,769,472 (2304*768)
#define OFF_WP  48854784             //    589,824 (768*768)  end: 49,444,608 halves

struct __align__(16) Half8 { __half h[8]; };
typedef _Float16 half8_t __attribute__((ext_vector_type(8)));
typedef _Float16 half4_t __attribute__((ext_vector_type(4)));
typedef float f32x4 __attribute__((ext_vector_type(4)));

__device__ __forceinline__ void gl16(const void* g, void* l) {
    __builtin_amdgcn_global_load_lds(
        (const __attribute__((address_space(1))) void*)g,
        (__attribute__((address_space(3))) void*)l, 16, 0, 0);
}

__device__ __forceinline__ half8_t cvt8(float4 u, float4 v) {
    return (half8_t){ (_Float16)u.x, (_Float16)u.y, (_Float16)u.z, (_Float16)u.w,
                      (_Float16)v.x, (_Float16)v.y, (_Float16)v.z, (_Float16)v.w };
}

// bijective XCD-chunked swizzle (m204)
__device__ __forceinline__ int xcd_swz(int o, int nwg) {
    const int q = nwg >> 3, r = nwg & 7;
    const int xcd = o & 7, idx = o >> 3;
    const int base = xcd < r ? xcd * (q + 1) : r * (q + 1) + (xcd - r) * q;
    return base + idx;
}

// ---------------------------------------------------------------------------
// K0: fp32 -> fp16 convert of qkv_w, proj_w only (x is fused into qkv GEMM)
// ---------------------------------------------------------------------------
#define NQ4 442368
#define NP4 147456
#define NW4 (NQ4+NP4)   // 589,824 = 2304 * 256

__global__ __launch_bounds__(256) void convert_f16(
    const float* __restrict__ wq, const float* __restrict__ wp,
    _Float16* __restrict__ wqo, _Float16* __restrict__ wpo)
{
    int i = blockIdx.x * 256 + threadIdx.x;
    const float4* s; _Float16* d; int o;
    if (i < NQ4) { s = (const float4*)wq; d = wqo; o = i; }
    else         { s = (const float4*)wp; d = wpo; o = i - NQ4; }
    float4 v = s[o];
    half4_t h = { (_Float16)v.x, (_Float16)v.y, (_Float16)v.z, (_Float16)v.w };
    *(half4_t*)&d[o * 4] = h;
}

// ---------------------------------------------------------------------------
// K1: qkv MFMA GEMM, BK=64, FUSED x f32->f16 (reg-staged A, T14 split),
//     B via global_load_lds, padded-M grid, vectorized epilogues.
// ---------------------------------------------------------------------------
#define QKV_NWG (18 * 100)   // 1800, divisible by 8

__global__ __launch_bounds__(256) void qkv_gemm_mfma(
    const float* __restrict__ Ax, const _Float16* __restrict__ Bw,
    _Float16* __restrict__ qh, _Float16* __restrict__ kh, _Float16* __restrict__ vth)
{
    __shared__ _Float16 Asl[2][128 * 64];    // [kk:2][128][32] logical
    __shared__ _Float16 Bsl[2][128 * 64];

    const int t  = threadIdx.x;
    const int w  = t >> 6;
    const int l  = t & 63;
    const int lr = l & 15;
    const int lg = l >> 4;
    const int wm = (w >> 1) * 64;
    const int wn = (w & 1) * 64;

    const int g   = xcd_swz(blockIdx.x, QKV_NWG);
    const int nt  = g % 18;
    const int n0  = nt * 128;
    const int mp0 = (g / 18) * 128;
    const int tsel  = nt / 6;          // 0=q 1=k 2=v
    const bool isV  = (tsel == 2);
    const int nbase = n0 - tsel * 768;

    const int row0 = t >> 2, row1 = 64 + (t >> 2);
    const int within = (t & 3) * 8;
    const int mpa0 = mp0 + row0, mpa1 = mp0 + row1;
    const int xra0 = (mpa0 / NP) * N_ + min(mpa0 % NP, N_ - 1);
    const int xra1 = (mpa1 / NP) * N_ + min(mpa1 % NP, N_ - 1);
    const float* Ag0 = Ax + (size_t)xra0 * 768 + within;
    const float* Ag1 = Ax + (size_t)xra1 * 768 + within;
    const _Float16* Bg0 = Bw + (size_t)(n0 + row0) * 768 + within;
    const _Float16* Bg1 = Bw + (size_t)(n0 + row1) * 768 + within;
    const int d0 = t * 8, d1 = (t + 256) * 8, d2 = (t + 512) * 8, d3 = (t + 768) * 8;

    f32x4 acc[4][4];
    #pragma unroll
    for (int i = 0; i < 4; ++i)
        #pragma unroll
        for (int j = 0; j < 4; ++j) acc[i][j] = (f32x4){0.f, 0.f, 0.f, 0.f};

    float4 ra[4][2];
    auto loadA = [&](int kn) {
        ra[0][0] = *(const float4*)(Ag0 + kn);      ra[0][1] = *(const float4*)(Ag0 + kn + 4);
        ra[1][0] = *(const float4*)(Ag1 + kn);      ra[1][1] = *(const float4*)(Ag1 + kn + 4);
        ra[2][0] = *(const float4*)(Ag0 + kn + 32); ra[2][1] = *(const float4*)(Ag0 + kn + 36);
        ra[3][0] = *(const float4*)(Ag1 + kn + 32); ra[3][1] = *(const float4*)(Ag1 + kn + 36);
    };
    auto writeA = [&](int buf) {
        *(half8_t*)&Asl[buf][d0] = cvt8(ra[0][0], ra[0][1]);
        *(half8_t*)&Asl[buf][d1] = cvt8(ra[1][0], ra[1][1]);
        *(half8_t*)&Asl[buf][d2] = cvt8(ra[2][0], ra[2][1]);
        *(half8_t*)&Asl[buf][d3] = cvt8(ra[3][0], ra[3][1]);
    };

    // prologue: stage K-tile 0 into buf 0
    loadA(0);
    gl16(Bg0, &Bsl[0][d0]); gl16(Bg1, &Bsl[0][d1]);
    gl16(Bg0 + 32, &Bsl[0][d2]); gl16(Bg1 + 32, &Bsl[0][d3]);
    writeA(0);
    __syncthreads();

    for (int it = 0; it < 12; ++it) {
        const int cur = it & 1;
        if (it < 11) {                  // issue next-tile loads early (T14)
            const int kn = (it + 1) * 64;
            loadA(kn);
            gl16(Bg0 + kn, &Bsl[cur ^ 1][d0]); gl16(Bg1 + kn, &Bsl[cur ^ 1][d1]);
            gl16(Bg0 + kn + 32, &Bsl[cur ^ 1][d2]); gl16(Bg1 + kn + 32, &Bsl[cur ^ 1][d3]);
        }
        #pragma unroll
        for (int kk = 0; kk < 2; ++kk) {
            const int kb = kk * 4096;
            half8_t af[4], bf[4];
            #pragma unroll
            for (int i = 0; i < 4; ++i)
                af[i] = *(const half8_t*)&Asl[cur][kb + (wm + i * 16 + lr) * 32 + lg * 8];
            #pragma unroll
            for (int j = 0; j < 4; ++j)
                bf[j] = *(const half8_t*)&Bsl[cur][kb + (wn + j * 16 + lr) * 32 + lg * 8];
            __builtin_amdgcn_s_setprio(1);
            if (!isV) {
                #pragma unroll
                for (int i = 0; i < 4; ++i)
                    #pragma unroll
                    for (int j = 0; j < 4; ++j)
                        acc[i][j] = __builtin_amdgcn_mfma_f32_16x16x32_f16(bf[j], af[i], acc[i][j], 0, 0, 0);
            } else {
                #pragma unroll
                for (int i = 0; i < 4; ++i)
                    #pragma unroll
                    for (int j = 0; j < 4; ++j)
                        acc[i][j] = __builtin_amdgcn_mfma_f32_16x16x32_f16(af[i], bf[j], acc[i][j], 0, 0, 0);
            }
            __builtin_amdgcn_s_setprio(0);
        }
        if (it < 11) writeA(cur ^ 1);   // late LDS write (loads landed under MFMA)
        __syncthreads();
    }

    if (!isV) {
        _Float16* dstb = (tsel == 0) ? qh : kh;
        const float sc  = (tsel == 0) ? SLOG2E : 1.0f;
        #pragma unroll
        for (int i = 0; i < 4; ++i) {
            const int mp = mp0 + wm + i * 16 + lr;
            const int bb = mp / NP;
            const int nn = mp - bb * NP;
            if (nn >= N_) continue;
            #pragma unroll
            for (int j = 0; j < 4; ++j) {
                const int nq = nbase + wn + j * 16 + lg * 4;
                const int hh = nq >> 6, dd = nq & 63;
                half4_t hv = { (_Float16)(acc[i][j][0] * sc), (_Float16)(acc[i][j][1] * sc),
                               (_Float16)(acc[i][j][2] * sc), (_Float16)(acc[i][j][3] * sc) };
                *(half4_t*)(dstb + ((size_t)(bb * H_ + hh) * N_ + nn) * HD_ + dd) = hv;
            }
        }
    } else {
        #pragma unroll
        for (int i = 0; i < 4; ++i) {
            const int mq  = mp0 + wm + i * 16 + lg * 4;
            const int bb  = mq / NP;
            const int nn0 = mq - bb * NP;
            if (nn0 >= N_) continue;
            const bool full = (nn0 + 3) < N_;
            #pragma unroll
            for (int j = 0; j < 4; ++j) {
                const int n  = nbase + wn + j * 16 + lr;
                const int hh = n >> 6, dd = n & 63;
                _Float16* vb = vth + ((size_t)(bb * H_ + hh) * HD_ + dd) * VTW;
                if (full) {
                    half4_t hv = { (_Float16)acc[i][j][0], (_Float16)acc[i][j][1],
                                   (_Float16)acc[i][j][2], (_Float16)acc[i][j][3] };
                    *(half4_t*)(vb + nn0) = hv;
                } else {
                    #pragma unroll
                    for (int r = 0; r < 4; ++r)
                        if (nn0 + r < N_) vb[nn0 + r] = (_Float16)acc[i][j][r];
                }
            }
        }
    }
}

// ---------------------------------------------------------------------------
// K2: pos bias (scaled by SCALE*log2e), f16 out: posh[h][n][m]
// ---------------------------------------------------------------------------
__global__ __launch_bounds__(256) void pos_kernel(
    const float* __restrict__ pe, const float* __restrict__ pw,
    __half* __restrict__ posh)
{
    __shared__ float W[H_][P_];
    const int t = threadIdx.x;
    for (int i = t; i < H_ * P_; i += 256) W[i / P_][i % P_] = pw[i];
    __syncthreads();
    int nm = blockIdx.x * 256 + t;
    if (nm >= N_ * N_) return;
    float e[48];
    const float4* src = (const float4*)(pe + (size_t)nm * 48);
    #pragma unroll
    for (int i = 0; i < 12; ++i) {
        float4 v = src[i];
        e[4*i] = v.x; e[4*i+1] = v.y; e[4*i+2] = v.z; e[4*i+3] = v.w;
    }
    int n = nm / N_, m = nm - n * N_;
    #pragma unroll
    for (int hh = 0; hh < H_; ++hh) {
        float s = 0.f;
        #pragma unroll
        for (int p = 0; p < 48; ++p) s = fmaf(e[p], W[hh][p], s);
        posh[((size_t)hh * N_ + n) * POSW + m] = __float2half(s * SLOG2E);
    }
}

// ---------------------------------------------------------------------------
// K3: MFMA flash attention (r13 structure) + virgin fast-path softmax
// ---------------------------------------------------------------------------
#define NQT 13
#define ATT_NWG (192 * NQT)   // 2496, divisible by 8

__global__ __launch_bounds__(256) void attn_mfma(
    const _Float16* __restrict__ qh, const _Float16* __restrict__ kh,
    const _Float16* __restrict__ vt, const _Float16* __restrict__ posh,
    _Float16* __restrict__ aoh)
{
    __shared__ _Float16 Kl[2][64][72];       // keys  [m][d]
    __shared__ _Float16 Vl[2][64][72];       // V^T   [d][sigma(m)] (permuted cols)

    const int t  = threadIdx.x;
    const int l  = t & 63;
    const int w  = t >> 6;
    const int lr = l & 15;
    const int lg = l >> 4;

    const int g2   = xcd_swz(blockIdx.x, ATT_NWG);
    const int qt   = g2 % NQT;
    const int rest = g2 / NQT;
    const int b    = rest & 15;
    const int h    = rest >> 4;
    const int bh   = b * H_ + h;
    const int n0   = qt * 64;

    const int qrow = n0 + w * 16 + lr;
    const int qrc  = qrow < N_ ? qrow : N_ - 1;
    const _Float16* qbase = qh + ((size_t)bh * N_ + qrc) * HD_;
    const half8_t qf0 = *(const half8_t*)(qbase + lg * 8);
    const half8_t qf1 = *(const half8_t*)(qbase + 32 + lg * 8);

    f32x4 O0 = {0.f,0.f,0.f,0.f}, O1 = O0, O2 = O0, O3 = O0;
    f32x4 lacc = {0.f,0.f,0.f,0.f};
    float m_run = 0.f;                       // virgin anchor
    bool  virgin = true;                     // wave-uniform: no rescale yet

    const half8_t vones = { (_Float16)1.f, (_Float16)1.f, (_Float16)1.f, (_Float16)1.f,
                            (_Float16)1.f, (_Float16)1.f, (_Float16)1.f, (_Float16)1.f };

    const int srow = t >> 2;
    const int scol = (t & 3) * 16;
    const int vbase = (scol & 32) + ((scol & 16) >> 2);
    const _Float16* kRow = kh + ((size_t)bh * N_) * HD_ + scol;
    const _Float16* vRow = vt + ((size_t)bh * HD_ + srow) * VTW + scol;
    const _Float16* bFrag = posh + ((size_t)h * N_ + qrc) * POSW + lg * 4;

    half8_t rk0, rk1, rv0, rv1;
    half4_t rbc[4], rbn[4];
    {
        const int gm = srow < N_ ? srow : N_ - 1;
        const half8_t* ks = (const half8_t*)(kRow + (size_t)gm * HD_);
        rk0 = ks[0]; rk1 = ks[1];
        const half8_t* vs = (const half8_t*)vRow;
        rv0 = vs[0]; rv1 = vs[1];
        #pragma unroll
        for (int ms = 0; ms < 4; ++ms)
            rbc[ms] = *(const half4_t*)(bFrag + ms * 16);
    }
    *(half8_t*)&Kl[0][srow][scol]     = rk0;
    *(half8_t*)&Kl[0][srow][scol + 8] = rk1;
    {
        _Float16* vd = &Vl[0][srow][vbase];
        *(half4_t*)(vd +  0) = __builtin_shufflevector(rv0, rv0, 0, 1, 2, 3);
        *(half4_t*)(vd +  8) = __builtin_shufflevector(rv0, rv0, 4, 5, 6, 7);
        *(half4_t*)(vd + 16) = __builtin_shufflevector(rv1, rv1, 0, 1, 2, 3);
        *(half4_t*)(vd + 24) = __builtin_shufflevector(rv1, rv1, 4, 5, 6, 7);
    }

    for (int c = 0; c < 13; ++c) {
        const int cur = c & 1;
        __syncthreads();                     // buf[cur] ready; buf[cur^1] free

        if (c < 12) {
            const int m0n = (c + 1) * 64;
            const int gm  = (m0n + srow) < N_ ? (m0n + srow) : N_ - 1;
            const half8_t* ks = (const half8_t*)(kRow + (size_t)gm * HD_);
            rk0 = ks[0]; rk1 = ks[1];
            const half8_t* vs = (const half8_t*)(vRow + m0n);
            rv0 = vs[0]; rv1 = vs[1];
            #pragma unroll
            for (int ms = 0; ms < 4; ++ms)
                rbn[ms] = *(const half4_t*)(bFrag + m0n + ms * 16);
        }

        // ---- QK^T swapped, f16 bias cvt as C-init
        f32x4 s[4];
        __builtin_amdgcn_s_setprio(1);
        #pragma unroll
        for (int ms = 0; ms < 4; ++ms) {
            f32x4 acc = { (float)rbc[ms][0], (float)rbc[ms][1],
                          (float)rbc[ms][2], (float)rbc[ms][3] };
            half8_t k0 = *(const half8_t*)&Kl[cur][ms * 16 + lr][lg * 8];
            half8_t k1 = *(const half8_t*)&Kl[cur][ms * 16 + lr][32 + lg * 8];
            acc = __builtin_amdgcn_mfma_f32_16x16x32_f16(k0, qf0, acc, 0, 0, 0);
            acc = __builtin_amdgcn_mfma_f32_16x16x32_f16(k1, qf1, acc, 0, 0, 0);
            s[ms] = acc;
        }
        __builtin_amdgcn_s_setprio(0);

        if (c == 12) {
            #pragma unroll
            for (int ms = 0; ms < 4; ++ms)
                #pragma unroll
                for (int r = 0; r < 4; ++r)
                    if (ms * 16 + lg * 4 + r >= 17) s[ms][r] = -1e30f;
        }

        // ---- defer-max softmax: common path has zero cross-lane ops
        float x0 = fmaxf(fmaxf(s[0][0], s[0][1]), s[0][2]);
        float x1 = fmaxf(fmaxf(s[0][3], s[1][0]), s[1][1]);
        float x2 = fmaxf(fmaxf(s[1][2], s[1][3]), s[2][0]);
        float x3 = fmaxf(fmaxf(s[2][1], s[2][2]), s[2][3]);
        float x4 = fmaxf(fmaxf(s[3][0], s[3][1]), s[3][2]);
        float mq = fmaxf(fmaxf(fmaxf(x0, x1), x2),
                         fmaxf(fmaxf(x3, x4), s[3][3]));

        if (__any(mq > m_run + 8.f)) {       // rare: reduce + rescale
            float v = fmaxf(mq, __shfl_xor(mq, 16));
            v = fmaxf(v, __shfl_xor(v, 32));
            const float mn    = fmaxf(m_run, v);
            const float alpha = exp2f(m_run - mn);
            m_run = mn;
            virgin = false;
            const float a0 = __shfl(alpha, lg * 4 + 0);
            const float a1 = __shfl(alpha, lg * 4 + 1);
            const float a2 = __shfl(alpha, lg * 4 + 2);
            const float a3 = __shfl(alpha, lg * 4 + 3);
            O0[0]*=a0; O0[1]*=a1; O0[2]*=a2; O0[3]*=a3;
            O1[0]*=a0; O1[1]*=a1; O1[2]*=a2; O1[3]*=a3;
            O2[0]*=a0; O2[1]*=a1; O2[2]*=a2; O2[3]*=a3;
            O3[0]*=a0; O3[1]*=a1; O3[2]*=a2; O3[3]*=a3;
            lacc[0]*=a0; lacc[1]*=a1; lacc[2]*=a2; lacc[3]*=a3;
        }

        float p[4][4];
        if (virgin) {                        // fast path: no subtraction
            #pragma unroll
            for (int ms = 0; ms < 4; ++ms)
                #pragma unroll
                for (int r = 0; r < 4; ++r)
                    p[ms][r] = exp2f(s[ms][r]);
        } else {
            #pragma unroll
            for (int ms = 0; ms < 4; ++ms)
                #pragma unroll
                for (int r = 0; r < 4; ++r)
                    p[ms][r] = exp2f(s[ms][r] - m_run);
        }

        half8_t pa0 = { (_Float16)p[0][0], (_Float16)p[0][1], (_Float16)p[0][2], (_Float16)p[0][3],
                        (_Float16)p[1][0], (_Float16)p[1][1], (_Float16)p[1][2], (_Float16)p[1][3] };
        half8_t pa1 = { (_Float16)p[2][0], (_Float16)p[2][1], (_Float16)p[2][2], (_Float16)p[2][3],
                        (_Float16)p[3][0], (_Float16)p[3][1], (_Float16)p[3][2], (_Float16)p[3][3] };

        // ---- PV + denominator; V B-frags are single b128 reads (permuted cols)
        __builtin_amdgcn_s_setprio(1);
        lacc = __builtin_amdgcn_mfma_f32_16x16x32_f16(pa0, vones, lacc, 0, 0, 0);
        lacc = __builtin_amdgcn_mfma_f32_16x16x32_f16(pa1, vones, lacc, 0, 0, 0);
        #pragma unroll
        for (int ds = 0; ds < 4; ++ds) {
            const _Float16* vr = &Vl[cur][ds * 16 + lr][0];
            half8_t vf0 = *(const half8_t*)&vr[lg * 8];
            half8_t vf1 = *(const half8_t*)&vr[32 + lg * 8];
            f32x4& Od = (ds == 0 ? O0 : ds == 1 ? O1 : ds == 2 ? O2 : O3);
            Od = __builtin_amdgcn_mfma_f32_16x16x32_f16(pa0, vf0, Od, 0, 0, 0);
            Od = __builtin_amdgcn_mfma_f32_16x16x32_f16(pa1, vf1, Od, 0, 0, 0);
        }
        __builtin_amdgcn_s_setprio(0);

        if (c < 12) {
            const int nxt = cur ^ 1;
            *(half8_t*)&Kl[nxt][srow][scol]     = rk0;
            *(half8_t*)&Kl[nxt][srow][scol + 8] = rk1;
            _Float16* vd = &Vl[nxt][srow][vbase];
            *(half4_t*)(vd +  0) = __builtin_shufflevector(rv0, rv0, 0, 1, 2, 3);
            *(half4_t*)(vd +  8) = __builtin_shufflevector(rv0, rv0, 4, 5, 6, 7);
            *(half4_t*)(vd + 16) = __builtin_shufflevector(rv1, rv1, 0, 1, 2, 3);
            *(half4_t*)(vd + 24) = __builtin_shufflevector(rv1, rv1, 4, 5, 6, 7);
            #pragma unroll
            for (int ms = 0; ms < 4; ++ms) rbc[ms] = rbn[ms];
        }
    }

    // ---- epilogue: lacc[r] IS l for q-row lg*4+r
    const int bb = bh / H_;
    #pragma unroll
    for (int r = 0; r < 4; ++r) {
        const int n = n0 + w * 16 + lg * 4 + r;
        if (n >= N_) continue;
        const float inv = 1.f / lacc[r];
        _Float16* dst = aoh + ((size_t)(bb * N_ + n)) * C_ + h * HD_;
        dst[0 * 16 + lr] = (_Float16)(O0[r] * inv);
        dst[1 * 16 + lr] = (_Float16)(O1[r] * inv);
        dst[2 * 16 + lr] = (_Float16)(O2[r] * inv);
        dst[3 * 16 + lr] = (_Float16)(O3[r] * inv);
    }
}

// ---------------------------------------------------------------------------
// K4: proj MFMA GEMM, BK=64, swapped operands -> aligned float4 stores
// ---------------------------------------------------------------------------
#define PROJ_NWG (6 * 99)

__global__ __launch_bounds__(256) void proj_gemm_mfma(
    const _Float16* __restrict__ A, const _Float16* __restrict__ Bw,
    const float* __restrict__ bias, float* __restrict__ out)
{
    __shared__ _Float16 Asl[2][128 * 64];
    __shared__ _Float16 Bsl[2][128 * 64];

    const int t  = threadIdx.x;
    const int w  = t >> 6;
    const int l  = t & 63;
    const int lr = l & 15;
    const int lg = l >> 4;
    const int wm = (w >> 1) * 64;
    const int wn = (w & 1) * 64;

    const int g  = xcd_swz(blockIdx.x, PROJ_NWG);
    const int n0 = (g % 6) * 128;
    const int m0 = (g / 6) * 128;

    const int row0 = t >> 2, row1 = 64 + (t >> 2);
    const int within = (t & 3) * 8;
    const int ma0 = min(m0 + row0, M_ - 1);
    const int ma1 = min(m0 + row1, M_ - 1);
    const _Float16* Ag0 = A  + (size_t)ma0 * 768 + within;
    const _Float16* Ag1 = A  + (size_t)ma1 * 768 + within;
    const _Float16* Bg0 = Bw + (size_t)(n0 + row0) * 768 + within;
    const _Float16* Bg1 = Bw + (size_t)(n0 + row1) * 768 + within;
    const int d0 = t * 8, d1 = (t + 256) * 8, d2 = (t + 512) * 8, d3 = (t + 768) * 8;

    f32x4 acc[4][4];
    #pragma unroll
    for (int i = 0; i < 4; ++i)
        #pragma unroll
        for (int j = 0; j < 4; ++j) acc[i][j] = (f32x4){0.f, 0.f, 0.f, 0.f};

    gl16(Ag0, &Asl[0][d0]); gl16(Ag1, &Asl[0][d1]);
    gl16(Ag0 + 32, &Asl[0][d2]); gl16(Ag1 + 32, &Asl[0][d3]);
    gl16(Bg0, &Bsl[0][d0]); gl16(Bg1, &Bsl[0][d1]);
    gl16(Bg0 + 32, &Bsl[0][d2]); gl16(Bg1 + 32, &Bsl[0][d3]);
    __syncthreads();

    for (int it = 0; it < 12; ++it) {
        const int cur = it & 1;
        if (it < 11) {
            const int kn = (it + 1) * 64;
            gl16(Ag0 + kn, &Asl[cur ^ 1][d0]); gl16(Ag1 + kn, &Asl[cur ^ 1][d1]);
            gl16(Ag0 + kn + 32, &Asl[cur ^ 1][d2]); gl16(Ag1 + kn + 32, &Asl[cur ^ 1][d3]);
            gl16(Bg0 + kn, &Bsl[cur ^ 1][d0]); gl16(Bg1 + kn, &Bsl[cur ^ 1][d1]);
            gl16(Bg0 + kn + 32, &Bsl[cur ^ 1][d2]); gl16(Bg1 + kn + 32, &Bsl[cur ^ 1][d3]);
        }
        #pragma unroll
        for (int kk = 0; kk < 2; ++kk) {
            const int kb = kk * 4096;
            half8_t af[4], bf[4];
            #pragma unroll
            for (int i = 0; i < 4; ++i)
                af[i] = *(const half8_t*)&Asl[cur][kb + (wm + i * 16 + lr) * 32 + lg * 8];
            #pragma unroll
            for (int j = 0; j < 4; ++j)
                bf[j] = *(const half8_t*)&Bsl[cur][kb + (wn + j * 16 + lr) * 32 + lg * 8];
            __builtin_amdgcn_s_setprio(1);
            #pragma unroll
            for (int i = 0; i < 4; ++i)
                #pragma unroll
                for (int j = 0; j < 4; ++j)
                    acc[i][j] = __builtin_amdgcn_mfma_f32_16x16x32_f16(bf[j], af[i], acc[i][j], 0, 0, 0);
            __builtin_amdgcn_s_setprio(0);
        }
        __syncthreads();
    }

    float4 bj4[4];
    #pragma unroll
    for (int j = 0; j < 4; ++j)
        bj4[j] = *(const float4*)&bias[n0 + wn + j * 16 + lg * 4];
    #pragma unroll
    for (int i = 0; i < 4; ++i) {
        const int m = m0 + wm + i * 16 + lr;
        if (m >= M_) continue;
        #pragma unroll
        for (int j = 0; j < 4; ++j) {
            const int nq = n0 + wn + j * 16 + lg * 4;
            float4 o = { acc[i][j][0] + bj4[j].x, acc[i][j][1] + bj4[j].y,
                         acc[i][j][2] + bj4[j].z, acc[i][j][3] + bj4[j].w };
            *(float4*)&out[(size_t)m * 768 + nq] = o;
        }
    }
}

// ---------------------------------------------------------------------------
extern "C" void kernel_launch(void* const* d_in, const int* in_sizes, int n_in,
                              void* d_out, int out_size, void* d_ws, size_t ws_size,
                              hipStream_t stream)
{
    const float* x     = (const float*)d_in[0];
    const float* qkv_w = (const float*)d_in[1];
    const float* pe    = (const float*)d_in[2];
    const float* pw    = (const float*)d_in[3];
    const float* pjw   = (const float*)d_in[4];
    const float* pjb   = (const float*)d_in[5];
    float* out = (float*)d_out;

    _Float16* wsh  = (_Float16*)d_ws;
    _Float16* qh   = wsh + OFF_Q;
    _Float16* kh   = wsh + OFF_K;
    _Float16* vth  = wsh + OFF_VT;
    _Float16* posh = wsh + OFF_POS;
    _Float16* aoh  = wsh + OFF_AO;
    _Float16* wqf  = wsh + OFF_WQ;
    _Float16* wpf  = wsh + OFF_WP;

    convert_f16<<<dim3(NW4 / 256), 256, 0, stream>>>(qkv_w, pjw, wqf, wpf);
    qkv_gemm_mfma<<<dim3(QKV_NWG), 256, 0, stream>>>(x, wqf, qh, kh, vth);
    pos_kernel<<<dim3((N_ * N_ + 255) / 256), 256, 0, stream>>>(pe, pw, (__half*)posh);
    attn_mfma<<<dim3(ATT_NWG), 256, 0, stream>>>(qh, kh, vth, posh, aoh);
    proj_gemm_mfma<<<dim3(PROJ_NWG), 256, 0, stream>>>(aoh, wpf, pjb, out);
}

// Round 17
// 252.542 us; speedup vs baseline: 1.0200x; 1.0200x over previous
//
#include <hip/hip_runtime.h>
#include <hip/hip_fp16.h>

#define B_ 16
#define N_ 785
#define NP 800          // padded per-batch rows (multiple of 4; 16*800=12800)
#define C_ 768
#define H_ 12
#define HD_ 64
#define P_ 48
#define M_ (B_*N_)      // 12560
#define MP_ (B_*NP)     // 12800 = 100 * 128
#define POSW 832        // padded row stride (halves) for pos bias (13*64)
#define VTW  832        // padded row stride (halves) for V^T
#define SLOG2E 0.1803368801111244f   // (hd^-0.5) * log2(e)

// ws layout (fp16 element offsets)
#define OFF_Q   0                    //  9,646,080
#define OFF_K   9646080              //  9,646,080
#define OFF_VT  19292160             // 10,223,616 (16*12*64*832)
#define OFF_POS 29515776             //  7,837,440 (12*785*832)
#define OFF_XF  37353216             //  9,732,096 (12672*768) — x-f16, later attn-out
#define OFF_AO  OFF_XF               //  alias: x dead after qkv_gemm
#define OFF_WQ  47085312             //  1,769,472 (2304*768)
#define OFF_WP  48854784             //    589,824 (768*768)  end: 49,444,608 halves

struct __align__(16) Half8 { __half h[8]; };
typedef _Float16 half8_t __attribute__((ext_vector_type(8)));
typedef _Float16 half4_t __attribute__((ext_vector_type(4)));
typedef float f32x4 __attribute__((ext_vector_type(4)));

__device__ __forceinline__ void gl16(const void* g, void* l) {
    __builtin_amdgcn_global_load_lds(
        (const __attribute__((address_space(1))) void*)g,
        (__attribute__((address_space(3))) void*)l, 16, 0, 0);
}

// bijective XCD-chunked swizzle (m204)
__device__ __forceinline__ int xcd_swz(int o, int nwg) {
    const int q = nwg >> 3, r = nwg & 7;
    const int xcd = o & 7, idx = o >> 3;
    const int base = xcd < r ? xcd * (q + 1) : r * (q + 1) + (xcd - r) * q;
    return base + idx;
}

// ---------------------------------------------------------------------------
// K0: fp32 -> fp16 convert of x, qkv_w, proj_w
// ---------------------------------------------------------------------------
#define NX4 2411520
#define NQ4 442368
#define NP4 147456
#define NTOT4 (NX4+NQ4+NP4)   // 3,001,344 = 11724 * 256

__global__ __launch_bounds__(256) void convert_f16(
    const float* __restrict__ x, const float* __restrict__ wq,
    const float* __restrict__ wp, _Float16* __restrict__ xo,
    _Float16* __restrict__ wqo, _Float16* __restrict__ wpo)
{
    int i = blockIdx.x * 256 + threadIdx.x;
    const float4* s; _Float16* d; int o;
    if (i < NX4)            { s = (const float4*)x;  d = xo;  o = i; }
    else if (i < NX4 + NQ4) { s = (const float4*)wq; d = wqo; o = i - NX4; }
    else                    { s = (const float4*)wp; d = wpo; o = i - NX4 - NQ4; }
    float4 v = s[o];
    half4_t h = { (_Float16)v.x, (_Float16)v.y, (_Float16)v.z, (_Float16)v.w };
    *(half4_t*)&d[o * 4] = h;
}

// ---------------------------------------------------------------------------
// K1: qkv MFMA GEMM, BK=64 (two [128][32] K-sub-blocks per barrier),
//     padded-M grid, vectorized epilogues (r15 verbatim).
// ---------------------------------------------------------------------------
#define QKV_NWG (18 * 100)   // 1800, divisible by 8

__global__ __launch_bounds__(256) void qkv_gemm_mfma(
    const _Float16* __restrict__ A, const _Float16* __restrict__ Bw,
    _Float16* __restrict__ qh, _Float16* __restrict__ kh, _Float16* __restrict__ vth)
{
    __shared__ _Float16 Asl[2][128 * 64];    // [kk:2][128][32] logical
    __shared__ _Float16 Bsl[2][128 * 64];

    const int t  = threadIdx.x;
    const int w  = t >> 6;
    const int l  = t & 63;
    const int lr = l & 15;
    const int lg = l >> 4;
    const int wm = (w >> 1) * 64;
    const int wn = (w & 1) * 64;

    const int g   = xcd_swz(blockIdx.x, QKV_NWG);
    const int nt  = g % 18;
    const int n0  = nt * 128;
    const int mp0 = (g / 18) * 128;
    const int tsel  = nt / 6;          // 0=q 1=k 2=v
    const bool isV  = (tsel == 2);
    const int nbase = n0 - tsel * 768;

    const int row0 = t >> 2, row1 = 64 + (t >> 2);
    const int within = (t & 3) * 8;
    const int mpa0 = mp0 + row0, mpa1 = mp0 + row1;
    const int xra0 = (mpa0 / NP) * N_ + min(mpa0 % NP, N_ - 1);
    const int xra1 = (mpa1 / NP) * N_ + min(mpa1 % NP, N_ - 1);
    const _Float16* Ag0 = A  + (size_t)xra0 * 768 + within;
    const _Float16* Ag1 = A  + (size_t)xra1 * 768 + within;
    const _Float16* Bg0 = Bw + (size_t)(n0 + row0) * 768 + within;
    const _Float16* Bg1 = Bw + (size_t)(n0 + row1) * 768 + within;
    const int d0 = t * 8, d1 = (t + 256) * 8, d2 = (t + 512) * 8, d3 = (t + 768) * 8;

    f32x4 acc[4][4];
    #pragma unroll
    for (int i = 0; i < 4; ++i)
        #pragma unroll
        for (int j = 0; j < 4; ++j) acc[i][j] = (f32x4){0.f, 0.f, 0.f, 0.f};

    gl16(Ag0, &Asl[0][d0]); gl16(Ag1, &Asl[0][d1]);
    gl16(Ag0 + 32, &Asl[0][d2]); gl16(Ag1 + 32, &Asl[0][d3]);
    gl16(Bg0, &Bsl[0][d0]); gl16(Bg1, &Bsl[0][d1]);
    gl16(Bg0 + 32, &Bsl[0][d2]); gl16(Bg1 + 32, &Bsl[0][d3]);
    __syncthreads();

    for (int it = 0; it < 12; ++it) {
        const int cur = it & 1;
        if (it < 11) {
            const int kn = (it + 1) * 64;
            gl16(Ag0 + kn, &Asl[cur ^ 1][d0]); gl16(Ag1 + kn, &Asl[cur ^ 1][d1]);
            gl16(Ag0 + kn + 32, &Asl[cur ^ 1][d2]); gl16(Ag1 + kn + 32, &Asl[cur ^ 1][d3]);
            gl16(Bg0 + kn, &Bsl[cur ^ 1][d0]); gl16(Bg1 + kn, &Bsl[cur ^ 1][d1]);
            gl16(Bg0 + kn + 32, &Bsl[cur ^ 1][d2]); gl16(Bg1 + kn + 32, &Bsl[cur ^ 1][d3]);
        }
        #pragma unroll
        for (int kk = 0; kk < 2; ++kk) {
            const int kb = kk * 4096;
            half8_t af[4], bf[4];
            #pragma unroll
            for (int i = 0; i < 4; ++i)
                af[i] = *(const half8_t*)&Asl[cur][kb + (wm + i * 16 + lr) * 32 + lg * 8];
            #pragma unroll
            for (int j = 0; j < 4; ++j)
                bf[j] = *(const half8_t*)&Bsl[cur][kb + (wn + j * 16 + lr) * 32 + lg * 8];
            __builtin_amdgcn_s_setprio(1);
            if (!isV) {
                #pragma unroll
                for (int i = 0; i < 4; ++i)
                    #pragma unroll
                    for (int j = 0; j < 4; ++j)
                        acc[i][j] = __builtin_amdgcn_mfma_f32_16x16x32_f16(bf[j], af[i], acc[i][j], 0, 0, 0);
            } else {
                #pragma unroll
                for (int i = 0; i < 4; ++i)
                    #pragma unroll
                    for (int j = 0; j < 4; ++j)
                        acc[i][j] = __builtin_amdgcn_mfma_f32_16x16x32_f16(af[i], bf[j], acc[i][j], 0, 0, 0);
            }
            __builtin_amdgcn_s_setprio(0);
        }
        __syncthreads();
    }

    if (!isV) {
        _Float16* dstb = (tsel == 0) ? qh : kh;
        const float sc  = (tsel == 0) ? SLOG2E : 1.0f;
        #pragma unroll
        for (int i = 0; i < 4; ++i) {
            const int mp = mp0 + wm + i * 16 + lr;
            const int bb = mp / NP;
            const int nn = mp - bb * NP;
            if (nn >= N_) continue;
            #pragma unroll
            for (int j = 0; j < 4; ++j) {
                const int nq = nbase + wn + j * 16 + lg * 4;
                const int hh = nq >> 6, dd = nq & 63;
                half4_t hv = { (_Float16)(acc[i][j][0] * sc), (_Float16)(acc[i][j][1] * sc),
                               (_Float16)(acc[i][j][2] * sc), (_Float16)(acc[i][j][3] * sc) };
                *(half4_t*)(dstb + ((size_t)(bb * H_ + hh) * N_ + nn) * HD_ + dd) = hv;
            }
        }
    } else {
        #pragma unroll
        for (int i = 0; i < 4; ++i) {
            const int mq  = mp0 + wm + i * 16 + lg * 4;
            const int bb  = mq / NP;
            const int nn0 = mq - bb * NP;
            if (nn0 >= N_) continue;
            const bool full = (nn0 + 3) < N_;
            #pragma unroll
            for (int j = 0; j < 4; ++j) {
                const int n  = nbase + wn + j * 16 + lr;
                const int hh = n >> 6, dd = n & 63;
                _Float16* vb = vth + ((size_t)(bb * H_ + hh) * HD_ + dd) * VTW;
                if (full) {
                    half4_t hv = { (_Float16)acc[i][j][0], (_Float16)acc[i][j][1],
                                   (_Float16)acc[i][j][2], (_Float16)acc[i][j][3] };
                    *(half4_t*)(vb + nn0) = hv;
                } else {
                    #pragma unroll
                    for (int r = 0; r < 4; ++r)
                        if (nn0 + r < N_) vb[nn0 + r] = (_Float16)acc[i][j][r];
                }
            }
        }
    }
}

// ---------------------------------------------------------------------------
// K2: pos bias (scaled by SCALE*log2e), f16 out: posh[h][n][m]
// ---------------------------------------------------------------------------
__global__ __launch_bounds__(256) void pos_kernel(
    const float* __restrict__ pe, const float* __restrict__ pw,
    __half* __restrict__ posh)
{
    __shared__ float W[H_][P_];
    const int t = threadIdx.x;
    for (int i = t; i < H_ * P_; i += 256) W[i / P_][i % P_] = pw[i];
    __syncthreads();
    int nm = blockIdx.x * 256 + t;
    if (nm >= N_ * N_) return;
    float e[48];
    const float4* src = (const float4*)(pe + (size_t)nm * 48);
    #pragma unroll
    for (int i = 0; i < 12; ++i) {
        float4 v = src[i];
        e[4*i] = v.x; e[4*i+1] = v.y; e[4*i+2] = v.z; e[4*i+3] = v.w;
    }
    int n = nm / N_, m = nm - n * N_;
    #pragma unroll
    for (int hh = 0; hh < H_; ++hh) {
        float s = 0.f;
        #pragma unroll
        for (int p = 0; p < 48; ++p) s = fmaf(e[p], W[hh][p], s);
        posh[((size_t)hh * N_ + n) * POSW + m] = __float2half(s * SLOG2E);
    }
}

// ---------------------------------------------------------------------------
// K3: MFMA flash attention: double-buffered K/V LDS, ONE barrier/chunk,
//     LDS commit moved BEFORE PV (overlaps ds_write with MFMA), virgin
//     fast-path softmax, pre-permuted V cols, f16 bias C-init, ones-MFMA l.
// ---------------------------------------------------------------------------
#define NQT 13
#define ATT_NWG (192 * NQT)   // 2496, divisible by 8

__global__ __launch_bounds__(256) void attn_mfma(
    const _Float16* __restrict__ qh, const _Float16* __restrict__ kh,
    const _Float16* __restrict__ vt, const _Float16* __restrict__ posh,
    _Float16* __restrict__ aoh)
{
    __shared__ _Float16 Kl[2][64][72];       // keys  [m][d]
    __shared__ _Float16 Vl[2][64][72];       // V^T   [d][sigma(m)] (permuted cols)

    const int t  = threadIdx.x;
    const int l  = t & 63;
    const int w  = t >> 6;
    const int lr = l & 15;
    const int lg = l >> 4;

    const int g2   = xcd_swz(blockIdx.x, ATT_NWG);
    const int qt   = g2 % NQT;
    const int rest = g2 / NQT;
    const int b    = rest & 15;
    const int h    = rest >> 4;
    const int bh   = b * H_ + h;
    const int n0   = qt * 64;

    const int qrow = n0 + w * 16 + lr;
    const int qrc  = qrow < N_ ? qrow : N_ - 1;
    const _Float16* qbase = qh + ((size_t)bh * N_ + qrc) * HD_;
    const half8_t qf0 = *(const half8_t*)(qbase + lg * 8);
    const half8_t qf1 = *(const half8_t*)(qbase + 32 + lg * 8);

    f32x4 O0 = {0.f,0.f,0.f,0.f}, O1 = O0, O2 = O0, O3 = O0;
    f32x4 lacc = {0.f,0.f,0.f,0.f};
    float m_run = 0.f;                       // virgin anchor
    bool  virgin = true;

    const half8_t vones = { (_Float16)1.f, (_Float16)1.f, (_Float16)1.f, (_Float16)1.f,
                            (_Float16)1.f, (_Float16)1.f, (_Float16)1.f, (_Float16)1.f };

    const int srow = t >> 2;
    const int scol = (t & 3) * 16;
    const int vbase = (scol & 32) + ((scol & 16) >> 2);
    const _Float16* kRow = kh + ((size_t)bh * N_) * HD_ + scol;
    const _Float16* vRow = vt + ((size_t)bh * HD_ + srow) * VTW + scol;
    const _Float16* bFrag = posh + ((size_t)h * N_ + qrc) * POSW + lg * 4;

    half8_t rk0, rk1, rv0, rv1;
    half4_t rbc[4], rbn[4];
    {
        const int gm = srow < N_ ? srow : N_ - 1;
        const half8_t* ks = (const half8_t*)(kRow + (size_t)gm * HD_);
        rk0 = ks[0]; rk1 = ks[1];
        const half8_t* vs = (const half8_t*)vRow;
        rv0 = vs[0]; rv1 = vs[1];
        #pragma unroll
        for (int ms = 0; ms < 4; ++ms)
            rbc[ms] = *(const half4_t*)(bFrag + ms * 16);
    }
    *(half8_t*)&Kl[0][srow][scol]     = rk0;
    *(half8_t*)&Kl[0][srow][scol + 8] = rk1;
    {
        _Float16* vd = &Vl[0][srow][vbase];
        *(half4_t*)(vd +  0) = __builtin_shufflevector(rv0, rv0, 0, 1, 2, 3);
        *(half4_t*)(vd +  8) = __builtin_shufflevector(rv0, rv0, 4, 5, 6, 7);
        *(half4_t*)(vd + 16) = __builtin_shufflevector(rv1, rv1, 0, 1, 2, 3);
        *(half4_t*)(vd + 24) = __builtin_shufflevector(rv1, rv1, 4, 5, 6, 7);
    }

    for (int c = 0; c < 13; ++c) {
        const int cur = c & 1;
        __syncthreads();                     // buf[cur] ready; buf[cur^1] free

        if (c < 12) {                        // issue next chunk's global loads
            const int m0n = (c + 1) * 64;
            const int gm  = (m0n + srow) < N_ ? (m0n + srow) : N_ - 1;
            const half8_t* ks = (const half8_t*)(kRow + (size_t)gm * HD_);
            rk0 = ks[0]; rk1 = ks[1];
            const half8_t* vs = (const half8_t*)(vRow + m0n);
            rv0 = vs[0]; rv1 = vs[1];
            #pragma unroll
            for (int ms = 0; ms < 4; ++ms)
                rbn[ms] = *(const half4_t*)(bFrag + m0n + ms * 16);
        }

        // ---- QK^T swapped, f16 bias cvt as C-init
        f32x4 s[4];
        __builtin_amdgcn_s_setprio(1);
        #pragma unroll
        for (int ms = 0; ms < 4; ++ms) {
            f32x4 acc = { (float)rbc[ms][0], (float)rbc[ms][1],
                          (float)rbc[ms][2], (float)rbc[ms][3] };
            half8_t k0 = *(const half8_t*)&Kl[cur][ms * 16 + lr][lg * 8];
            half8_t k1 = *(const half8_t*)&Kl[cur][ms * 16 + lr][32 + lg * 8];
            acc = __builtin_amdgcn_mfma_f32_16x16x32_f16(k0, qf0, acc, 0, 0, 0);
            acc = __builtin_amdgcn_mfma_f32_16x16x32_f16(k1, qf1, acc, 0, 0, 0);
            s[ms] = acc;
        }
        __builtin_amdgcn_s_setprio(0);

        if (c == 12) {
            #pragma unroll
            for (int ms = 0; ms < 4; ++ms)
                #pragma unroll
                for (int r = 0; r < 4; ++r)
                    if (ms * 16 + lg * 4 + r >= 17) s[ms][r] = -1e30f;
        }

        // ---- defer-max softmax: common path has zero cross-lane ops
        float x0 = fmaxf(fmaxf(s[0][0], s[0][1]), s[0][2]);
        float x1 = fmaxf(fmaxf(s[0][3], s[1][0]), s[1][1]);
        float x2 = fmaxf(fmaxf(s[1][2], s[1][3]), s[2][0]);
        float x3 = fmaxf(fmaxf(s[2][1], s[2][2]), s[2][3]);
        float x4 = fmaxf(fmaxf(s[3][0], s[3][1]), s[3][2]);
        float mq = fmaxf(fmaxf(fmaxf(x0, x1), x2),
                         fmaxf(fmaxf(x3, x4), s[3][3]));

        if (__any(mq > m_run + 8.f)) {       // rare: reduce + rescale
            float v = fmaxf(mq, __shfl_xor(mq, 16));
            v = fmaxf(v, __shfl_xor(v, 32));
            const float mn    = fmaxf(m_run, v);
            const float alpha = exp2f(m_run - mn);
            m_run = mn;
            virgin = false;
            const float a0 = __shfl(alpha, lg * 4 + 0);
            const float a1 = __shfl(alpha, lg * 4 + 1);
            const float a2 = __shfl(alpha, lg * 4 + 2);
            const float a3 = __shfl(alpha, lg * 4 + 3);
            O0[0]*=a0; O0[1]*=a1; O0[2]*=a2; O0[3]*=a3;
            O1[0]*=a0; O1[1]*=a1; O1[2]*=a2; O1[3]*=a3;
            O2[0]*=a0; O2[1]*=a1; O2[2]*=a2; O2[3]*=a3;
            O3[0]*=a0; O3[1]*=a1; O3[2]*=a2; O3[3]*=a3;
            lacc[0]*=a0; lacc[1]*=a1; lacc[2]*=a2; lacc[3]*=a3;
        }

        float p[4][4];
        if (virgin) {                        // fast path: no subtraction
            #pragma unroll
            for (int ms = 0; ms < 4; ++ms)
                #pragma unroll
                for (int r = 0; r < 4; ++r)
                    p[ms][r] = exp2f(s[ms][r]);
        } else {
            #pragma unroll
            for (int ms = 0; ms < 4; ++ms)
                #pragma unroll
                for (int r = 0; r < 4; ++r)
                    p[ms][r] = exp2f(s[ms][r] - m_run);
        }

        half8_t pa0 = { (_Float16)p[0][0], (_Float16)p[0][1], (_Float16)p[0][2], (_Float16)p[0][3],
                        (_Float16)p[1][0], (_Float16)p[1][1], (_Float16)p[1][2], (_Float16)p[1][3] };
        half8_t pa1 = { (_Float16)p[2][0], (_Float16)p[2][1], (_Float16)p[2][2], (_Float16)p[2][3],
                        (_Float16)p[3][0], (_Float16)p[3][1], (_Float16)p[3][2], (_Float16)p[3][3] };

        // ---- commit prefetched chunk c+1 BEFORE PV: ds_writes drain under MFMA
        if (c < 12) {
            const int nxt = cur ^ 1;
            *(half8_t*)&Kl[nxt][srow][scol]     = rk0;
            *(half8_t*)&Kl[nxt][srow][scol + 8] = rk1;
            _Float16* vd = &Vl[nxt][srow][vbase];
            *(half4_t*)(vd +  0) = __builtin_shufflevector(rv0, rv0, 0, 1, 2, 3);
            *(half4_t*)(vd +  8) = __builtin_shufflevector(rv0, rv0, 4, 5, 6, 7);
            *(half4_t*)(vd + 16) = __builtin_shufflevector(rv1, rv1, 0, 1, 2, 3);
            *(half4_t*)(vd + 24) = __builtin_shufflevector(rv1, rv1, 4, 5, 6, 7);
            #pragma unroll
            for (int ms = 0; ms < 4; ++ms) rbc[ms] = rbn[ms];
        }

        // ---- PV + denominator; V B-frags are single b128 reads (permuted cols)
        __builtin_amdgcn_s_setprio(1);
        lacc = __builtin_amdgcn_mfma_f32_16x16x32_f16(pa0, vones, lacc, 0, 0, 0);
        lacc = __builtin_amdgcn_mfma_f32_16x16x32_f16(pa1, vones, lacc, 0, 0, 0);
        #pragma unroll
        for (int ds = 0; ds < 4; ++ds) {
            const _Float16* vr = &Vl[cur][ds * 16 + lr][0];
            half8_t vf0 = *(const half8_t*)&vr[lg * 8];
            half8_t vf1 = *(const half8_t*)&vr[32 + lg * 8];
            f32x4& Od = (ds == 0 ? O0 : ds == 1 ? O1 : ds == 2 ? O2 : O3);
            Od = __builtin_amdgcn_mfma_f32_16x16x32_f16(pa0, vf0, Od, 0, 0, 0);
            Od = __builtin_amdgcn_mfma_f32_16x16x32_f16(pa1, vf1, Od, 0, 0, 0);
        }
        __builtin_amdgcn_s_setprio(0);
    }

    // ---- epilogue: lacc[r] IS l for q-row lg*4+r
    const int bb = bh / H_;
    #pragma unroll
    for (int r = 0; r < 4; ++r) {
        const int n = n0 + w * 16 + lg * 4 + r;
        if (n >= N_) continue;
        const float inv = 1.f / lacc[r];
        _Float16* dst = aoh + ((size_t)(bb * N_ + n)) * C_ + h * HD_;
        dst[0 * 16 + lr] = (_Float16)(O0[r] * inv);
        dst[1 * 16 + lr] = (_Float16)(O1[r] * inv);
        dst[2 * 16 + lr] = (_Float16)(O2[r] * inv);
        dst[3 * 16 + lr] = (_Float16)(O3[r] * inv);
    }
}

// ---------------------------------------------------------------------------
// K4: proj MFMA GEMM, BK=64, swapped operands -> aligned float4 stores
// ---------------------------------------------------------------------------
#define PROJ_NWG (6 * 99)

__global__ __launch_bounds__(256) void proj_gemm_mfma(
    const _Float16* __restrict__ A, const _Float16* __restrict__ Bw,
    const float* __restrict__ bias, float* __restrict__ out)
{
    __shared__ _Float16 Asl[2][128 * 64];
    __shared__ _Float16 Bsl[2][128 * 64];

    const int t  = threadIdx.x;
    const int w  = t >> 6;
    const int l  = t & 63;
    const int lr = l & 15;
    const int lg = l >> 4;
    const int wm = (w >> 1) * 64;
    const int wn = (w & 1) * 64;

    const int g  = xcd_swz(blockIdx.x, PROJ_NWG);
    const int n0 = (g % 6) * 128;
    const int m0 = (g / 6) * 128;

    const int row0 = t >> 2, row1 = 64 + (t >> 2);
    const int within = (t & 3) * 8;
    const int ma0 = min(m0 + row0, M_ - 1);
    const int ma1 = min(m0 + row1, M_ - 1);
    const _Float16* Ag0 = A  + (size_t)ma0 * 768 + within;
    const _Float16* Ag1 = A  + (size_t)ma1 * 768 + within;
    const _Float16* Bg0 = Bw + (size_t)(n0 + row0) * 768 + within;
    const _Float16* Bg1 = Bw + (size_t)(n0 + row1) * 768 + within;
    const int d0 = t * 8, d1 = (t + 256) * 8, d2 = (t + 512) * 8, d3 = (t + 768) * 8;

    f32x4 acc[4][4];
    #pragma unroll
    for (int i = 0; i < 4; ++i)
        #pragma unroll
        for (int j = 0; j < 4; ++j) acc[i][j] = (f32x4){0.f, 0.f, 0.f, 0.f};

    gl16(Ag0, &Asl[0][d0]); gl16(Ag1, &Asl[0][d1]);
    gl16(Ag0 + 32, &Asl[0][d2]); gl16(Ag1 + 32, &Asl[0][d3]);
    gl16(Bg0, &Bsl[0][d0]); gl16(Bg1, &Bsl[0][d1]);
    gl16(Bg0 + 32, &Bsl[0][d2]); gl16(Bg1 + 32, &Bsl[0][d3]);
    __syncthreads();

    for (int it = 0; it < 12; ++it) {
        const int cur = it & 1;
        if (it < 11) {
            const int kn = (it + 1) * 64;
            gl16(Ag0 + kn, &Asl[cur ^ 1][d0]); gl16(Ag1 + kn, &Asl[cur ^ 1][d1]);
            gl16(Ag0 + kn + 32, &Asl[cur ^ 1][d2]); gl16(Ag1 + kn + 32, &Asl[cur ^ 1][d3]);
            gl16(Bg0 + kn, &Bsl[cur ^ 1][d0]); gl16(Bg1 + kn, &Bsl[cur ^ 1][d1]);
            gl16(Bg0 + kn + 32, &Bsl[cur ^ 1][d2]); gl16(Bg1 + kn + 32, &Bsl[cur ^ 1][d3]);
        }
        #pragma unroll
        for (int kk = 0; kk < 2; ++kk) {
            const int kb = kk * 4096;
            half8_t af[4], bf[4];
            #pragma unroll
            for (int i = 0; i < 4; ++i)
                af[i] = *(const half8_t*)&Asl[cur][kb + (wm + i * 16 + lr) * 32 + lg * 8];
            #pragma unroll
            for (int j = 0; j < 4; ++j)
                bf[j] = *(const half8_t*)&Bsl[cur][kb + (wn + j * 16 + lr) * 32 + lg * 8];
            __builtin_amdgcn_s_setprio(1);
            #pragma unroll
            for (int i = 0; i < 4; ++i)
                #pragma unroll
                for (int j = 0; j < 4; ++j)
                    acc[i][j] = __builtin_amdgcn_mfma_f32_16x16x32_f16(bf[j], af[i], acc[i][j], 0, 0, 0);
            __builtin_amdgcn_s_setprio(0);
        }
        __syncthreads();
    }

    float4 bj4[4];
    #pragma unroll
    for (int j = 0; j < 4; ++j)
        bj4[j] = *(const float4*)&bias[n0 + wn + j * 16 + lg * 4];
    #pragma unroll
    for (int i = 0; i < 4; ++i) {
        const int m = m0 + wm + i * 16 + lr;
        if (m >= M_) continue;
        #pragma unroll
        for (int j = 0; j < 4; ++j) {
            const int nq = n0 + wn + j * 16 + lg * 4;
            float4 o = { acc[i][j][0] + bj4[j].x, acc[i][j][1] + bj4[j].y,
                         acc[i][j][2] + bj4[j].z, acc[i][j][3] + bj4[j].w };
            *(float4*)&out[(size_t)m * 768 + nq] = o;
        }
    }
}

// ---------------------------------------------------------------------------
extern "C" void kernel_launch(void* const* d_in, const int* in_sizes, int n_in,
                              void* d_out, int out_size, void* d_ws, size_t ws_size,
                              hipStream_t stream)
{
    const float* x     = (const float*)d_in[0];
    const float* qkv_w = (const float*)d_in[1];
    const float* pe    = (const float*)d_in[2];
    const float* pw    = (const float*)d_in[3];
    const float* pjw   = (const float*)d_in[4];
    const float* pjb   = (const float*)d_in[5];
    float* out = (float*)d_out;

    _Float16* wsh  = (_Float16*)d_ws;
    _Float16* qh   = wsh + OFF_Q;
    _Float16* kh   = wsh + OFF_K;
    _Float16* vth  = wsh + OFF_VT;
    _Float16* posh = wsh + OFF_POS;
    _Float16* xf   = wsh + OFF_XF;
    _Float16* aoh  = wsh + OFF_AO;       // aliases xf (x dead after qkv_gemm)
    _Float16* wqf  = wsh + OFF_WQ;
    _Float16* wpf  = wsh + OFF_WP;

    convert_f16<<<dim3(NTOT4 / 256), 256, 0, stream>>>(x, qkv_w, pjw, xf, wqf, wpf);
    qkv_gemm_mfma<<<dim3(QKV_NWG), 256, 0, stream>>>(xf, wqf, qh, kh, vth);
    pos_kernel<<<dim3((N_ * N_ + 255) / 256), 256, 0, stream>>>(pe, pw, (__half*)posh);
    attn_mfma<<<dim3(ATT_NWG), 256, 0, stream>>>(qh, kh, vth, posh, aoh);
    proj_gemm_mfma<<<dim3(PROJ_NWG), 256, 0, stream>>>(aoh, wpf, pjb, out);
}